// Round 4
// baseline (186.099 us; speedup 1.0000x reference)
//
#include <hip/hip_runtime.h>
#include <hip/hip_bf16.h>
#include <math.h>

#define NP 4096      // N
#define DD 128       // D
#define N2 8192      // 2N
#define TINV 10.0f   // 1/temperature
#define SHIFT 10.0f  // fixed lse shift (sim <= 10)
#define C1 14.4269504f       // TINV * log2(e): e = 2^(C1*(acc-1))
#define NGL2 -0.0288539004f  // -GAMMA1 * log2(e), GAMMA1 = 0.02

typedef __attribute__((ext_vector_type(8))) short bf16x8;
typedef __attribute__((ext_vector_type(4))) float f32x4;
typedef __attribute__((ext_vector_type(4))) int i32x4;

// sum over each 16-lane DPP row; result lands in lane (lane&15)==0 of each row
__device__ __forceinline__ float dpp_red16(float x) {
  x += __int_as_float(__builtin_amdgcn_update_dpp(0, __float_as_int(x), 0x101, 0xF, 0xF, true));
  x += __int_as_float(__builtin_amdgcn_update_dpp(0, __float_as_int(x), 0x102, 0xF, 0xF, true));
  x += __int_as_float(__builtin_amdgcn_update_dpp(0, __float_as_int(x), 0x104, 0xF, 0xF, true));
  x += __int_as_float(__builtin_amdgcn_update_dpp(0, __float_as_int(x), 0x108, 0xF, 0xF, true));
  return x;
}

// ---------------- prep: knorm (blocks 0..2047) || klabel (blocks 2048..6143) ----------------
// rowinfo = (y1, TINV/rs1, y2, TINV/rs2)
__global__ __launch_bounds__(256) void kprep(const float* __restrict__ zi,
                                             const float* __restrict__ zj,
                                             const float* __restrict__ labels,
                                             __hip_bfloat16* __restrict__ Z,
                                             float4* __restrict__ rowinfo,
                                             double* __restrict__ accd,
                                             unsigned int* __restrict__ cnt) {
  int w = threadIdx.x >> 6, lane = threadIdx.x & 63;
  if (blockIdx.x < 2048) {
    // ---- normalize rows -> bf16 ----
    int a = blockIdx.x * 4 + w;
    const float* src = (a < NP) ? (zi + (size_t)a * DD) : (zj + (size_t)(a - NP) * DD);
    float2 v = *(const float2*)(src + lane * 2);
    float ss = v.x * v.x + v.y * v.y;
#pragma unroll
    for (int m = 1; m < 64; m <<= 1) ss += __shfl_xor(ss, m);
    float rn = rsqrtf(ss);
    __hip_bfloat162 o;
    o.x = __float2bfloat16(v.x * rn);
    o.y = __float2bfloat16(v.y * rn);
    *(__hip_bfloat162*)(Z + (size_t)a * DD + lane * 2) = o;
  } else {
    // ---- label row sums ----
    int a = blockIdx.x - 2048;  // 0..NP-1
    if (a == 0 && threadIdx.x == 0) { *accd = 0.0; *cnt = 0u; }  // reset final accum (read in kreduce only)
    float ca = labels[a * 2 + 0], ga = labels[a * 2 + 1];
    float s1 = 0.f, c2 = 0.f;
    for (int m = threadIdx.x; m < NP; m += 256) {
      float2 lm = *(const float2*)(labels + m * 2);
      float dy = ca - lm.x;
      s1 += __builtin_amdgcn_exp2f(dy * dy * NGL2);
      c2 += (ga == lm.y) ? 1.f : 0.f;
    }
#pragma unroll
    for (int m = 1; m < 64; m <<= 1) {
      s1 += __shfl_xor(s1, m);
      c2 += __shfl_xor(c2, m);
    }
    __shared__ float sh[8];
    if (lane == 0) { sh[w] = s1; sh[4 + w] = c2; }
    __syncthreads();
    if (threadIdx.x == 0) {
      s1 = sh[0] + sh[1] + sh[2] + sh[3];
      c2 = sh[4] + sh[5] + sh[6] + sh[7];
      float rs1 = 2.f * s1 - 1.f;         // cont row sum over 8192, diag removed
      float rs2 = (float)NP + c2 - 1.f;   // cat row sum = 4095 + class count
      float4 ri = make_float4(ca, TINV / rs1, ga, TINV / rs2);
      rowinfo[a] = ri;
      rowinfo[a + NP] = ri;
    }
  }
}

// ---------------- main: upper-triangular 128x128 tiles, per-wave float4 partials ----------------
// part[tb] = float4[4][128]: slot wc (0,1) row-side, slot 2+wr col-side.
// float4 = (exp-sum, cont-weighted-sim (scaled by TINV/rs1), sum v, sum same-class v)
__global__ __launch_bounds__(256, 3) void kmain(const __hip_bfloat16* __restrict__ Zp,
                                                const float4* __restrict__ rowinfo,
                                                float4* __restrict__ part) {
  __shared__ char lds[2 * 128 * 128];  // A half-K panel + B half-K panel, 32 KiB
  char* ldsA = lds;
  char* ldsB = lds + 128 * 128;

  // triangular decode: largest I with I*(129-I)/2 <= tb
  int tb = blockIdx.x;
  int I = (int)((129.0f - sqrtf(16641.0f - 8.0f * (float)tb)) * 0.5f);
  while (I * (129 - I) / 2 > tb) --I;
  while ((I + 1) * (128 - I) / 2 <= tb) ++I;
  int J = I + (tb - I * (129 - I) / 2);
  const bool diag = (I == J);
  const int row0 = I * 128, col0 = J * 128;
  const int t = threadIdx.x;
  const char* gZ = (const char*)Zp;  // [8192][256B]
  const char* ldsBp = diag ? ldsA : ldsB;

  const int lane = t & 63, w = t >> 6;
  const int wr = w >> 1, wc = w & 1;
  const int lrow = lane & 15, lgrp = lane >> 4;

  f32x4 acc[4][4] = {};
#pragma unroll
  for (int kh = 0; kh < 2; ++kh) {  // two K-halves of 64
    if (kh) __syncthreads();
#pragma unroll
    for (int i = 0; i < 4; ++i) {   // stage A half: 1024 x 16B chunks
      int chunk = t + i * 256;
      int r = chunk >> 3;
      int bc = (chunk & 7) << 4;
      int swz = bc ^ ((r & 7) << 4);
      i32x4 va = *(const i32x4*)(gZ + (size_t)(row0 + r) * 256 + kh * 128 + bc);
      *(i32x4*)(ldsA + r * 128 + swz) = va;
    }
    if (!diag) {
#pragma unroll
      for (int i = 0; i < 4; ++i) {
        int chunk = t + i * 256;
        int r = chunk >> 3;
        int bc = (chunk & 7) << 4;
        int swz = bc ^ ((r & 7) << 4);
        i32x4 vb = *(const i32x4*)(gZ + (size_t)(col0 + r) * 256 + kh * 128 + bc);
        *(i32x4*)(ldsB + r * 128 + swz) = vb;
      }
    }
    __syncthreads();
#pragma unroll
    for (int kk = 0; kk < 2; ++kk) {
      int bcol = kk * 64 + (lgrp << 4);
      bf16x8 af[4], bfv[4];
#pragma unroll
      for (int mi = 0; mi < 4; ++mi) {
        int r = wr * 64 + mi * 16 + lrow;
        af[mi] = *(const bf16x8*)(ldsA + r * 128 + (bcol ^ ((r & 7) << 4)));
      }
#pragma unroll
      for (int ni = 0; ni < 4; ++ni) {
        int r = wc * 64 + ni * 16 + lrow;
        bfv[ni] = *(const bf16x8*)(ldsBp + r * 128 + (bcol ^ ((r & 7) << 4)));
      }
#pragma unroll
      for (int mi = 0; mi < 4; ++mi)
#pragma unroll
        for (int ni = 0; ni < 4; ++ni)
          acc[mi][ni] = __builtin_amdgcn_mfma_f32_16x16x32_bf16(af[mi], bfv[ni], acc[mi][ni], 0, 0, 0);
    }
  }

  // epilogue. acc element j of (mi,ni): row a = row0+wr*64+mi*16+lgrp*4+j, col b = col0+wc*64+ni*16+lrow
  float4 rbv[4];
  int bcols[4];
#pragma unroll
  for (int ni = 0; ni < 4; ++ni) {
    int b = col0 + wc * 64 + ni * 16 + lrow;
    rbv[ni] = rowinfo[b];
    bcols[ni] = b;
  }

  float ec[4] = {0.f, 0.f, 0.f, 0.f}, pc[4] = {0.f, 0.f, 0.f, 0.f};
  float sc[4] = {0.f, 0.f, 0.f, 0.f}, mc[4] = {0.f, 0.f, 0.f, 0.f};

#pragma unroll
  for (int mi = 0; mi < 4; ++mi) {
    int a0 = row0 + wr * 64 + mi * 16 + lgrp * 4;
#pragma unroll
    for (int j = 0; j < 4; ++j) {
      int a = a0 + j;
      float4 ri = rowinfo[a];
      float es = 0.f, pa = 0.f, sv = 0.f, ma = 0.f;
#pragma unroll
      for (int ni = 0; ni < 4; ++ni) {
        float v = acc[mi][ni][j];
        float nd = (diag && a == bcols[ni]) ? 0.f : 1.f;  // exclude diagonal element
        float e = __builtin_amdgcn_exp2f(fmaf(v, C1, -C1)) * nd;  // exp(sim-10)
        float dy = ri.x - rbv[ni].x;
        float wu = __builtin_amdgcn_exp2f(dy * dy * NGL2) * nd;   // exp(-g*dy^2)
        float sm = ((ri.z == rbv[ni].z) ? 1.f : 0.f) * nd;        // same class
        float vn = v * nd;
        es += e;
        ec[ni] += e;
        pa = fmaf(wu, v, pa);
        pc[ni] = fmaf(wu, v, pc[ni]);
        sv += vn;
        sc[ni] += vn;
        ma = fmaf(sm, v, ma);
        mc[ni] = fmaf(sm, v, mc[ni]);
      }
      es = dpp_red16(es);
      pa = dpp_red16(pa);
      sv = dpp_red16(sv);
      ma = dpp_red16(ma);
      if (lrow == 0) {
        int idx = wr * 64 + mi * 16 + lgrp * 4 + j;
        part[((size_t)tb * 4 + wc) * 128 + idx] = make_float4(es, pa * ri.y, sv, ma);
      }
    }
  }

  if (!diag) {
    // column-side (transpose) contributions: reduce over lgrp groups
#pragma unroll
    for (int ni = 0; ni < 4; ++ni) {
      float e2 = ec[ni] + __shfl_xor(ec[ni], 16);
      e2 += __shfl_xor(e2, 32);
      float p2 = pc[ni] + __shfl_xor(pc[ni], 16);
      p2 += __shfl_xor(p2, 32);
      float s2 = sc[ni] + __shfl_xor(sc[ni], 16);
      s2 += __shfl_xor(s2, 32);
      float m2 = mc[ni] + __shfl_xor(mc[ni], 16);
      m2 += __shfl_xor(m2, 32);
      if (lane < 16) {
        int idx = wc * 64 + ni * 16 + lane;
        part[((size_t)tb * 4 + 2 + wr) * 128 + idx] = make_float4(e2, p2 * rbv[ni].y, s2, m2);
      }
    }
  }
}

// ---------------- reduce: fold slots per row-tile, apply cat + log, global double-accumulate ----------------
__global__ __launch_bounds__(128) void kreduce(const float4* __restrict__ part,
                                               const float4* __restrict__ rowinfo,
                                               double* __restrict__ accd,
                                               unsigned int* __restrict__ cnt,
                                               float* __restrict__ out) {
  int T = blockIdx.x;   // 0..63
  int r = threadIdx.x;  // 0..127
  float es = 0.f, ws = 0.f, sv = 0.f, ma = 0.f;
  int tb0 = T * (129 - T) / 2;
  for (int k = 0; k < 64 - T; ++k) {  // row-side: tiles (T, J>=T)
    size_t base = ((size_t)(tb0 + k) * 4) * 128 + r;
    float4 v0 = part[base];
    float4 v1 = part[base + 128];
    es += v0.x + v1.x;
    ws += v0.y + v1.y;
    sv += v0.z + v1.z;
    ma += v0.w + v1.w;
  }
  for (int I = 0; I < T; ++I) {       // col-side: tiles (I<T, T)
    size_t base = ((size_t)(I * (129 - I) / 2 + T - I) * 4 + 2) * 128 + r;
    float4 v0 = part[base];
    float4 v1 = part[base + 128];
    es += v0.x + v1.x;
    ws += v0.y + v1.y;
    sv += v0.z + v1.z;
    ma += v0.w + v1.w;
  }
  float4 ri = rowinfo[T * 128 + r];
  float cat = 0.5f * (sv + ma) * ri.w;  // ri.w = TINV/rs2
  double val = (double)(ws + cat) - 2.0 * (double)(SHIFT + __logf(es));
#pragma unroll
  for (int m = 1; m < 64; m <<= 1) val += __shfl_xor(val, m);
  __shared__ double sh[2];
  if ((threadIdx.x & 63) == 0) sh[threadIdx.x >> 6] = val;
  __syncthreads();
  if (threadIdx.x == 0) {
    double bsum = sh[0] + sh[1];
    atomicAdd(accd, bsum);
    __threadfence();
    unsigned int old = atomicAdd(cnt, 1u);
    if (old == 63u) {  // last block finishes the loss
      double tot = atomicAdd(accd, 0.0);  // coherent device-scope read
      out[0] = (float)(-tot / (double)NP);
    }
  }
}

extern "C" void kernel_launch(void* const* d_in, const int* in_sizes, int n_in,
                              void* d_out, int out_size, void* d_ws, size_t ws_size,
                              hipStream_t stream) {
  const float* zi = (const float*)d_in[0];
  const float* zj = (const float*)d_in[1];
  const float* labels = (const float*)d_in[2];
  float* out = (float*)d_out;
  char* ws = (char*)d_ws;

  float4* rowinfo = (float4*)ws;                           // 128 KiB
  double* accd = (double*)(ws + 128 * 1024);               // 8 B
  unsigned int* cnt = (unsigned int*)(ws + 128 * 1024 + 8);
  __hip_bfloat16* Z = (__hip_bfloat16*)(ws + 256 * 1024);  // 2 MiB
  float4* part = (float4*)(ws + 256 * 1024 + 2 * 1024 * 1024);  // 2080*4*128*16B = 17 MiB

  kprep<<<6144, 256, 0, stream>>>(zi, zj, labels, Z, rowinfo, accd, cnt);
  kmain<<<2080, 256, 0, stream>>>(Z, rowinfo, part);
  kreduce<<<64, 128, 0, stream>>>(part, rowinfo, accd, cnt, out);
}